// Round 1
// baseline (132.773 us; speedup 1.0000x reference)
//
#include <hip/hip_runtime.h>

#define NB 16
#define NCH 6
#define BATCH 8
#define PLANE (512*512)
#define CHUNKS 64
#define THREADS 256
#define PX_PER_BLOCK (PLANE / CHUNKS)       // 4096
#define ITERS (PX_PER_BLOCK / THREADS)      // 16

#if __has_builtin(__builtin_amdgcn_exp2f)
__device__ __forceinline__ float exp2_fast(float x) { return __builtin_amdgcn_exp2f(x); }
#else
__device__ __forceinline__ float exp2_fast(float x) { return __expf(x * 0.69314718056f); }
#endif

// weight = exp(-128*(x - i/15)^2) = exp2( -(128*log2(e)/225) * (15x - i)^2 )
#define NEG_C2 (-0.8207331788f)

__global__ __launch_bounds__(THREADS, 2)
void hist_kernel(const float* __restrict__ pred,
                 const float* __restrict__ tgt,
                 float* __restrict__ hist /* [6][BATCH][NB]; h = c + 3*tensor */)
{
    const int chunk = blockIdx.x;
    const int b     = blockIdx.y;
    const int tid   = threadIdx.x;

    float acc[NCH][NB];
    #pragma unroll
    for (int h = 0; h < NCH; ++h)
        #pragma unroll
        for (int i = 0; i < NB; ++i)
            acc[h][i] = 0.0f;

    const float* pb = pred + (size_t)b * 3 * PLANE;
    const float* tb = tgt  + (size_t)b * 3 * PLANE;
    const int base = chunk * PX_PER_BLOCK + tid;

    for (int it = 0; it < ITERS; ++it) {
        const int p = base + it * THREADS;
        const float p0 = pb[p];
        const float p1 = pb[p + PLANE];
        const float p2 = pb[p + 2 * PLANE];
        const float t0 = tb[p];
        const float t1 = tb[p + PLANE];
        const float t2 = tb[p + 2 * PLANE];

        // mask from target brightness (mean over channels > 0.4)
        const float br = (t0 + t1 + t2) * (1.0f / 3.0f);
        const float m  = br > 0.4f ? 1.0f : 0.0f;

        const float xs[NCH] = {p0, p1, p2, t0, t1, t2};
        #pragma unroll
        for (int h = 0; h < NCH; ++h) {
            const float y = xs[h] * 15.0f;
            #pragma unroll
            for (int i = 0; i < NB; ++i) {
                const float u = y - (float)i;
                const float w = exp2_fast(u * u * NEG_C2);
                acc[h][i] = fmaf(w, m, acc[h][i]);
            }
        }
    }

    // ---- reduction: wave shuffle -> LDS cross-wave -> global atomics ----
    __shared__ float red[4][NCH * NB];
    const int lane = tid & 63;
    const int wv   = tid >> 6;

    #pragma unroll
    for (int h = 0; h < NCH; ++h) {
        #pragma unroll
        for (int i = 0; i < NB; ++i) {
            float v = acc[h][i];
            #pragma unroll
            for (int off = 32; off > 0; off >>= 1)
                v += __shfl_down(v, off, 64);
            if (lane == 0) red[wv][h * NB + i] = v;
        }
    }
    __syncthreads();
    if (tid < NCH * NB) {
        const float s = red[0][tid] + red[1][tid] + red[2][tid] + red[3][tid];
        const int h = tid / NB;
        const int i = tid % NB;
        atomicAdd(&hist[(h * BATCH + b) * NB + i], s);
    }
}

__global__ void finalize_kernel(const float* __restrict__ hist,
                                float* __restrict__ out)
{
    const int t = threadIdx.x;      // 384 threads: one (b,c,bin) each
    const int b   = t / 48;
    const int rem = t % 48;
    const int c   = rem / NB;
    const int i   = rem % NB;

    const float* hp = hist + ((size_t)(c    ) * BATCH + b) * NB;  // pred
    const float* ht = hist + ((size_t)(c + 3) * BATCH + b) * NB;  // target
    float sp = 0.0f, st = 0.0f;
    #pragma unroll
    for (int k = 0; k < NB; ++k) { sp += hp[k]; st += ht[k]; }

    float val = fabsf(hp[i] / (sp + 1e-7f) - ht[i] / (st + 1e-7f));

    #pragma unroll
    for (int off = 32; off > 0; off >>= 1)
        val += __shfl_down(val, off, 64);

    __shared__ float r[6];
    const int lane = t & 63, wv = t >> 6;
    if (lane == 0) r[wv] = val;
    __syncthreads();
    if (t == 0)
        out[0] = (r[0] + r[1] + r[2] + r[3] + r[4] + r[5]) * (1.0f / 384.0f);
}

extern "C" void kernel_launch(void* const* d_in, const int* in_sizes, int n_in,
                              void* d_out, int out_size, void* d_ws, size_t ws_size,
                              hipStream_t stream)
{
    const float* pred = (const float*)d_in[0];
    const float* tgt  = (const float*)d_in[1];
    float* hist = (float*)d_ws;   // 768 floats

    hipMemsetAsync(hist, 0, NCH * BATCH * NB * sizeof(float), stream);
    hist_kernel<<<dim3(CHUNKS, BATCH), THREADS, 0, stream>>>(pred, tgt, hist);
    finalize_kernel<<<1, 384, 0, stream>>>(hist, (float*)d_out);
}

// Round 2
// 119.304 us; speedup vs baseline: 1.1129x; 1.1129x over previous
//
#include <hip/hip_runtime.h>

#define NB 16
#define BATCH 8
#define PLANE (512*512)          // 262144 px per channel plane
#define CHUNKS 64
#define THREADS 256
#define PX_PER_BLOCK (PLANE / CHUNKS)        // 4096
#define GROUPS (PX_PER_BLOCK / (THREADS*4))  // 4 iters of float4

#if __has_builtin(__builtin_amdgcn_exp2f)
__device__ __forceinline__ float exp2_fast(float x) { return __builtin_amdgcn_exp2f(x); }
#else
__device__ __forceinline__ float exp2_fast(float x) { return __expf(x * 0.69314718056f); }
#endif

// weight = exp(-128*(x - i/15)^2) = exp2( -(128*log2(e)/225) * (15x - i)^2 )
#define NEG_C2 (-0.8207331788f)
#define SENTINEL 1.0e9f

// ---------------------------------------------------------------------------
// 1) brightness mask, bit-packed: bit g of maskbits <=> pixel g (g = b*PLANE+hw)
// ---------------------------------------------------------------------------
__global__ __launch_bounds__(THREADS)
void mask_kernel(const float* __restrict__ tgt,
                 unsigned long long* __restrict__ maskbits)
{
    const int g  = blockIdx.x * THREADS + threadIdx.x;   // 0 .. 2M-1
    const int b  = g >> 18;
    const int hw = g & (PLANE - 1);
    const float* tb = tgt + (size_t)b * 3 * PLANE + hw;
    const float t0 = tb[0];
    const float t1 = tb[PLANE];
    const float t2 = tb[2 * PLANE];
    const bool m = (t0 + t1 + t2) * (1.0f / 3.0f) > 0.4f;
    const unsigned long long bm = __ballot(m);
    if ((threadIdx.x & 63) == 0)
        maskbits[(blockIdx.x << 2) + (threadIdx.x >> 6)] = bm;
}

// ---------------------------------------------------------------------------
// 2) per-channel-tensor soft histogram. blockIdx.z = h in [0,6):
//    h<3 -> pred channel h ; h>=3 -> target channel h-3
// ---------------------------------------------------------------------------
__global__ __launch_bounds__(THREADS, 8)
void hist_kernel(const float* __restrict__ pred,
                 const float* __restrict__ tgt,
                 const unsigned int* __restrict__ mask32,
                 float* __restrict__ hist /* [6][BATCH][NB] */)
{
    const int chunk = blockIdx.x;
    const int b     = blockIdx.y;
    const int h     = blockIdx.z;
    const int tid   = threadIdx.x;

    const float* src = (h < 3 ? pred : tgt)
                     + (size_t)b * 3 * PLANE + (size_t)(h % 3) * PLANE;

    float acc[NB];
    #pragma unroll
    for (int i = 0; i < NB; ++i) acc[i] = 0.0f;

    const int base = chunk * PX_PER_BLOCK + tid * 4;

    #pragma unroll
    for (int g = 0; g < GROUPS; ++g) {
        const int p = base + g * (THREADS * 4);
        const float4 xv = *(const float4*)(src + p);
        const unsigned int gp = ((unsigned)b << 18) + (unsigned)p;
        const unsigned int word = mask32[gp >> 5];
        const unsigned int bits = (word >> (p & 31)) & 0xFu;

        const float xs[4] = {xv.x, xv.y, xv.z, xv.w};
        #pragma unroll
        for (int j = 0; j < 4; ++j) {
            const float y = ((bits >> j) & 1u) ? xs[j] * 15.0f : SENTINEL;
            #pragma unroll
            for (int i = 0; i < NB; ++i) {
                const float u = y - (float)i;
                acc[i] += exp2_fast(u * u * NEG_C2);
            }
        }
    }

    // wave shuffle -> LDS cross-wave -> global atomics
    __shared__ float red[4][NB];
    const int lane = tid & 63;
    const int wv   = tid >> 6;

    #pragma unroll
    for (int i = 0; i < NB; ++i) {
        float v = acc[i];
        #pragma unroll
        for (int off = 32; off > 0; off >>= 1)
            v += __shfl_down(v, off, 64);
        if (lane == 0) red[wv][i] = v;
    }
    __syncthreads();
    if (tid < NB) {
        const float s = red[0][tid] + red[1][tid] + red[2][tid] + red[3][tid];
        atomicAdd(&hist[(h * BATCH + b) * NB + tid], s);
    }
}

// ---------------------------------------------------------------------------
// 3) normalize + L1 + mean
// ---------------------------------------------------------------------------
__global__ void finalize_kernel(const float* __restrict__ hist,
                                float* __restrict__ out)
{
    const int t = threadIdx.x;      // 384 threads: one (b,c,bin) each
    const int b   = t / 48;
    const int rem = t % 48;
    const int c   = rem / NB;
    const int i   = rem % NB;

    const float* hp = hist + ((size_t)(c    ) * BATCH + b) * NB;  // pred
    const float* ht = hist + ((size_t)(c + 3) * BATCH + b) * NB;  // target
    float sp = 0.0f, st = 0.0f;
    #pragma unroll
    for (int k = 0; k < NB; ++k) { sp += hp[k]; st += ht[k]; }

    float val = fabsf(hp[i] / (sp + 1e-7f) - ht[i] / (st + 1e-7f));

    #pragma unroll
    for (int off = 32; off > 0; off >>= 1)
        val += __shfl_down(val, off, 64);

    __shared__ float r[6];
    const int lane = t & 63, wv = t >> 6;
    if (lane == 0) r[wv] = val;
    __syncthreads();
    if (t == 0)
        out[0] = (r[0] + r[1] + r[2] + r[3] + r[4] + r[5]) * (1.0f / 384.0f);
}

extern "C" void kernel_launch(void* const* d_in, const int* in_sizes, int n_in,
                              void* d_out, int out_size, void* d_ws, size_t ws_size,
                              hipStream_t stream)
{
    const float* pred = (const float*)d_in[0];
    const float* tgt  = (const float*)d_in[1];

    float* hist = (float*)d_ws;                               // 768 floats
    unsigned long long* maskbits =
        (unsigned long long*)((char*)d_ws + 4096);            // 262144 bytes

    hipMemsetAsync(hist, 0, 6 * BATCH * NB * sizeof(float), stream);

    const int total_px = BATCH * PLANE;                       // 2,097,152
    mask_kernel<<<total_px / THREADS, THREADS, 0, stream>>>(tgt, maskbits);

    hist_kernel<<<dim3(CHUNKS, BATCH, 6), THREADS, 0, stream>>>(
        pred, tgt, (const unsigned int*)maskbits, hist);

    finalize_kernel<<<1, 384, 0, stream>>>(hist, (float*)d_out);
}

// Round 3
// 100.158 us; speedup vs baseline: 1.3256x; 1.1911x over previous
//
#include <hip/hip_runtime.h>

#define NB 16
#define BATCH 8
#define PLANE (512*512)           // 262144 px per channel plane
#define FBINS 1024                // fine histogram resolution
#define CHUNKS 128
#define THREADS 256
#define PX_PER_BLOCK (PLANE / CHUNKS)          // 2048
#define GROUPS (PX_PER_BLOCK / (THREADS * 4))  // 2 float4 iters

#if __has_builtin(__builtin_amdgcn_exp2f)
__device__ __forceinline__ float exp2_fast(float x) { return __builtin_amdgcn_exp2f(x); }
#else
__device__ __forceinline__ float exp2_fast(float x) { return __expf(x * 0.69314718056f); }
#endif

// weight = exp(-128*(x - i/15)^2) = exp2( -(128*log2(e)/225) * (15x - i)^2 )
#define NEG_C2 (-0.8207331788f)

__device__ __forceinline__ int qbin(float x) {
    int f = (int)(x * (float)FBINS);
    return f > (FBINS - 1) ? (FBINS - 1) : f;
}

// ---------------------------------------------------------------------------
// 1) masked fine histogram. LDS: 3 arrays of 1024 u32, each word packs two
//    channels (lo16 = ch 2k, hi16 = ch 2k+1). Max count/half = 2048 -> no carry.
//    Channel order h in [0,6): p0,p1,p2,t0,t1,t2.
// ---------------------------------------------------------------------------
__global__ __launch_bounds__(THREADS)
void count_kernel(const float* __restrict__ pred,
                  const float* __restrict__ tgt,
                  unsigned int* __restrict__ partial
                  /* [3][BATCH][CHUNKS][FBINS] */)
{
    const int chunk = blockIdx.x;
    const int b     = blockIdx.y;
    const int tid   = threadIdx.x;

    __shared__ unsigned int cnt[3 * FBINS];   // 12 KB
    #pragma unroll
    for (int k = 0; k < 3 * FBINS / THREADS; ++k)
        cnt[tid + k * THREADS] = 0u;
    __syncthreads();

    const float* pb = pred + (size_t)b * 3 * PLANE;
    const float* tb = tgt  + (size_t)b * 3 * PLANE;
    const int base = chunk * PX_PER_BLOCK + tid * 4;

    #pragma unroll
    for (int g = 0; g < GROUPS; ++g) {
        const int p = base + g * (THREADS * 4);
        const float4 P0 = *(const float4*)(pb + p);
        const float4 P1 = *(const float4*)(pb + PLANE + p);
        const float4 P2 = *(const float4*)(pb + 2 * PLANE + p);
        const float4 T0 = *(const float4*)(tb + p);
        const float4 T1 = *(const float4*)(tb + PLANE + p);
        const float4 T2 = *(const float4*)(tb + 2 * PLANE + p);

        const float p0a[4] = {P0.x, P0.y, P0.z, P0.w};
        const float p1a[4] = {P1.x, P1.y, P1.z, P1.w};
        const float p2a[4] = {P2.x, P2.y, P2.z, P2.w};
        const float t0a[4] = {T0.x, T0.y, T0.z, T0.w};
        const float t1a[4] = {T1.x, T1.y, T1.z, T1.w};
        const float t2a[4] = {T2.x, T2.y, T2.z, T2.w};

        #pragma unroll
        for (int j = 0; j < 4; ++j) {
            const bool m = (t0a[j] + t1a[j] + t2a[j]) * (1.0f / 3.0f) > 0.4f;
            if (m) {
                atomicAdd(&cnt[           qbin(p0a[j])], 1u);       // h=0 lo
                atomicAdd(&cnt[           qbin(p1a[j])], 65536u);   // h=1 hi
                atomicAdd(&cnt[FBINS    + qbin(p2a[j])], 1u);       // h=2 lo
                atomicAdd(&cnt[FBINS    + qbin(t0a[j])], 65536u);   // h=3 hi
                atomicAdd(&cnt[2*FBINS  + qbin(t1a[j])], 1u);       // h=4 lo
                atomicAdd(&cnt[2*FBINS  + qbin(t2a[j])], 65536u);   // h=5 hi
            }
        }
    }
    __syncthreads();

    // flush 3072 words -> partial[h2][b][chunk][f]
    #pragma unroll
    for (int k = 0; k < 3 * FBINS / THREADS; ++k) {
        const int w  = tid + k * THREADS;
        const int h2 = w >> 10;
        const int f  = w & (FBINS - 1);
        partial[(((size_t)h2 * BATCH + b) * CHUNKS + chunk) * FBINS + f] = cnt[w];
    }
}

// ---------------------------------------------------------------------------
// 2) reduce partials + Gaussian convolution -> hist[6][BATCH][NB]
//    one block per (h, b); hb = h*BATCH + b
// ---------------------------------------------------------------------------
__global__ __launch_bounds__(THREADS)
void combine_kernel(const unsigned int* __restrict__ partial,
                    float* __restrict__ hist)
{
    const int hb  = blockIdx.x;        // 0..47
    const int h   = hb / BATCH;
    const int b   = hb % BATCH;
    const int h2  = h >> 1;
    const int sh  = (h & 1) * 16;
    const int tid = threadIdx.x;

    // each thread owns 4 consecutive fine bins: f = tid*4 + j
    unsigned int s[4] = {0u, 0u, 0u, 0u};
    const unsigned int* base =
        partial + (((size_t)h2 * BATCH + b) * CHUNKS) * FBINS + tid * 4;
    for (int c = 0; c < CHUNKS; ++c) {
        const uint4 v = *(const uint4*)(base + (size_t)c * FBINS);
        s[0] += (v.x >> sh) & 0xFFFFu;
        s[1] += (v.y >> sh) & 0xFFFFu;
        s[2] += (v.z >> sh) & 0xFFFFu;
        s[3] += (v.w >> sh) & 0xFFFFu;
    }

    float acc[NB];
    #pragma unroll
    for (int i = 0; i < NB; ++i) acc[i] = 0.0f;

    #pragma unroll
    for (int j = 0; j < 4; ++j) {
        const float cf = (float)s[j];
        const float y  = ((float)(tid * 4 + j) + 0.5f) * (15.0f / (float)FBINS);
        #pragma unroll
        for (int i = 0; i < NB; ++i) {
            const float u = y - (float)i;
            acc[i] = fmaf(cf, exp2_fast(u * u * NEG_C2), acc[i]);
        }
    }

    // wave shuffle -> cross-wave LDS -> store (no atomics: block owns hb)
    __shared__ float red[4][NB];
    const int lane = tid & 63;
    const int wv   = tid >> 6;
    #pragma unroll
    for (int i = 0; i < NB; ++i) {
        float v = acc[i];
        #pragma unroll
        for (int off = 32; off > 0; off >>= 1)
            v += __shfl_down(v, off, 64);
        if (lane == 0) red[wv][i] = v;
    }
    __syncthreads();
    if (tid < NB)
        hist[(size_t)hb * NB + tid] =
            red[0][tid] + red[1][tid] + red[2][tid] + red[3][tid];
}

// ---------------------------------------------------------------------------
// 3) normalize + L1 + mean
// ---------------------------------------------------------------------------
__global__ void finalize_kernel(const float* __restrict__ hist,
                                float* __restrict__ out)
{
    const int t = threadIdx.x;      // 384 threads: one (b,c,bin) each
    const int b   = t / 48;
    const int rem = t % 48;
    const int c   = rem / NB;
    const int i   = rem % NB;

    const float* hp = hist + ((size_t)(c    ) * BATCH + b) * NB;  // pred
    const float* ht = hist + ((size_t)(c + 3) * BATCH + b) * NB;  // target
    float sp = 0.0f, st = 0.0f;
    #pragma unroll
    for (int k = 0; k < NB; ++k) { sp += hp[k]; st += ht[k]; }

    float val = fabsf(hp[i] / (sp + 1e-7f) - ht[i] / (st + 1e-7f));

    #pragma unroll
    for (int off = 32; off > 0; off >>= 1)
        val += __shfl_down(val, off, 64);

    __shared__ float r[6];
    const int lane = t & 63, wv = t >> 6;
    if (lane == 0) r[wv] = val;
    __syncthreads();
    if (t == 0)
        out[0] = (r[0] + r[1] + r[2] + r[3] + r[4] + r[5]) * (1.0f / 384.0f);
}

extern "C" void kernel_launch(void* const* d_in, const int* in_sizes, int n_in,
                              void* d_out, int out_size, void* d_ws, size_t ws_size,
                              hipStream_t stream)
{
    const float* pred = (const float*)d_in[0];
    const float* tgt  = (const float*)d_in[1];

    unsigned int* partial = (unsigned int*)d_ws;  // 3*8*128*1024*4 = 12.58 MB
    float* hist = (float*)((char*)d_ws + (size_t)3 * BATCH * CHUNKS * FBINS * 4);

    count_kernel<<<dim3(CHUNKS, BATCH), THREADS, 0, stream>>>(pred, tgt, partial);
    combine_kernel<<<6 * BATCH, THREADS, 0, stream>>>(partial, hist);
    finalize_kernel<<<1, 384, 0, stream>>>(hist, (float*)d_out);
}

// Round 4
// 90.890 us; speedup vs baseline: 1.4608x; 1.1020x over previous
//
#include <hip/hip_runtime.h>

#define NB 16
#define BATCH 8
#define PLANE (512*512)           // 262144 px per channel plane
#define FBINS 512                 // fine histogram resolution
#define CHUNKS 128
#define THREADS 256
#define PX_PER_BLOCK (PLANE / CHUNKS)          // 2048
#define GROUPS (PX_PER_BLOCK / (THREADS * 4))  // 2 float4 iters
#define SLICES 8                               // fine-bin slices in combine
#define FPB (FBINS / SLICES)                   // 64 fine bins per combine block

#if __has_builtin(__builtin_amdgcn_exp2f)
__device__ __forceinline__ float exp2_fast(float x) { return __builtin_amdgcn_exp2f(x); }
#else
__device__ __forceinline__ float exp2_fast(float x) { return __expf(x * 0.69314718056f); }
#endif

// weight = exp(-128*(x - i/15)^2) = exp2( -(128*log2(e)/225) * (15x - i)^2 )
#define NEG_C2 (-0.8207331788f)

__device__ __forceinline__ int qbin(float x) {
    int f = (int)(x * (float)FBINS);
    return f > (FBINS - 1) ? (FBINS - 1) : f;
}

// ---------------------------------------------------------------------------
// 1) masked fine histogram. LDS: 3 arrays of FBINS u32, each word packs two
//    channels (lo16 = ch 2k, hi16 = ch 2k+1). Max count/half = 2048 -> no carry.
//    Channel order h in [0,6): p0,p1,p2,t0,t1,t2.
// ---------------------------------------------------------------------------
__global__ __launch_bounds__(THREADS)
void count_kernel(const float* __restrict__ pred,
                  const float* __restrict__ tgt,
                  unsigned int* __restrict__ partial
                  /* [3][BATCH][CHUNKS][FBINS] */)
{
    const int chunk = blockIdx.x;
    const int b     = blockIdx.y;
    const int tid   = threadIdx.x;

    __shared__ unsigned int cnt[3 * FBINS];   // 6 KB
    #pragma unroll
    for (int k = 0; k < 3 * FBINS / THREADS; ++k)
        cnt[tid + k * THREADS] = 0u;
    __syncthreads();

    const float* pb = pred + (size_t)b * 3 * PLANE;
    const float* tb = tgt  + (size_t)b * 3 * PLANE;
    const int base = chunk * PX_PER_BLOCK + tid * 4;

    #pragma unroll
    for (int g = 0; g < GROUPS; ++g) {
        const int p = base + g * (THREADS * 4);
        const float4 P0 = *(const float4*)(pb + p);
        const float4 P1 = *(const float4*)(pb + PLANE + p);
        const float4 P2 = *(const float4*)(pb + 2 * PLANE + p);
        const float4 T0 = *(const float4*)(tb + p);
        const float4 T1 = *(const float4*)(tb + PLANE + p);
        const float4 T2 = *(const float4*)(tb + 2 * PLANE + p);

        const float p0a[4] = {P0.x, P0.y, P0.z, P0.w};
        const float p1a[4] = {P1.x, P1.y, P1.z, P1.w};
        const float p2a[4] = {P2.x, P2.y, P2.z, P2.w};
        const float t0a[4] = {T0.x, T0.y, T0.z, T0.w};
        const float t1a[4] = {T1.x, T1.y, T1.z, T1.w};
        const float t2a[4] = {T2.x, T2.y, T2.z, T2.w};

        #pragma unroll
        for (int j = 0; j < 4; ++j) {
            const bool m = (t0a[j] + t1a[j] + t2a[j]) * (1.0f / 3.0f) > 0.4f;
            if (m) {
                atomicAdd(&cnt[           qbin(p0a[j])], 1u);       // h=0 lo
                atomicAdd(&cnt[           qbin(p1a[j])], 65536u);   // h=1 hi
                atomicAdd(&cnt[FBINS    + qbin(p2a[j])], 1u);       // h=2 lo
                atomicAdd(&cnt[FBINS    + qbin(t0a[j])], 65536u);   // h=3 hi
                atomicAdd(&cnt[2*FBINS  + qbin(t1a[j])], 1u);       // h=4 lo
                atomicAdd(&cnt[2*FBINS  + qbin(t2a[j])], 65536u);   // h=5 hi
            }
        }
    }
    __syncthreads();

    // flush 1536 words -> partial[h2][b][chunk][f]
    #pragma unroll
    for (int k = 0; k < 3 * FBINS / THREADS; ++k) {
        const int w  = tid + k * THREADS;
        const int h2 = w >> 9;
        const int f  = w & (FBINS - 1);
        partial[(((size_t)h2 * BATCH + b) * CHUNKS + chunk) * FBINS + f] = cnt[w];
    }
}

// ---------------------------------------------------------------------------
// 2) reduce partials over chunks + Gaussian conv -> out2[slice][hb][NB]
//    grid (SLICES, 48). Thread t: f_loc = t&63, quarter q = t>>6 sums 32 chunks.
// ---------------------------------------------------------------------------
__global__ __launch_bounds__(THREADS)
void combine_kernel(const unsigned int* __restrict__ partial,
                    float* __restrict__ out2 /* [SLICES][48][NB] */)
{
    const int slice = blockIdx.x;
    const int hb    = blockIdx.y;      // h*BATCH + b
    const int h     = hb / BATCH;
    const int b     = hb % BATCH;
    const int h2    = h >> 1;
    const int sh    = (h & 1) * 16;
    const int tid   = threadIdx.x;

    const int f_loc = tid & (FPB - 1);
    const int q     = tid >> 6;        // 0..3, chunk quarter
    const int f     = slice * FPB + f_loc;

    const unsigned int* base =
        partial + (((size_t)h2 * BATCH + b) * CHUNKS + q * 32) * FBINS + f;
    unsigned int s = 0u;
    #pragma unroll 8
    for (int c = 0; c < 32; ++c)
        s += (base[(size_t)c * FBINS] >> sh) & 0xFFFFu;

    __shared__ unsigned int red[4][FPB];
    red[q][f_loc] = s;
    __syncthreads();

    if (tid < FPB) {   // wave 0 only
        const float cf = (float)(red[0][tid] + red[1][tid] + red[2][tid] + red[3][tid]);
        const float y  = ((float)(slice * FPB + tid) + 0.5f) * (15.0f / (float)FBINS);

        float acc[NB];
        #pragma unroll
        for (int i = 0; i < NB; ++i) {
            const float u = y - (float)i;
            acc[i] = cf * exp2_fast(u * u * NEG_C2);
        }
        #pragma unroll
        for (int off = 32; off > 0; off >>= 1)
            #pragma unroll
            for (int i = 0; i < NB; ++i)
                acc[i] += __shfl_down(acc[i], off, 64);

        if (tid == 0) {
            float* o = out2 + ((size_t)slice * 48 + hb) * NB;
            #pragma unroll
            for (int i = 0; i < NB; ++i) o[i] = acc[i];
        }
    }
}

// ---------------------------------------------------------------------------
// 3) sum slices, normalize, L1, mean
// ---------------------------------------------------------------------------
__global__ void finalize_kernel(const float* __restrict__ out2,
                                float* __restrict__ out)
{
    const int t = threadIdx.x;      // 384 threads
    __shared__ float H[48 * NB];    // [h*BATCH+b][i]

    for (int e = t; e < 48 * NB; e += 384) {
        float v = 0.0f;
        #pragma unroll
        for (int s = 0; s < SLICES; ++s)
            v += out2[(size_t)s * 48 * NB + e];
        H[e] = v;
    }
    __syncthreads();

    const int b   = t / 48;
    const int rem = t % 48;
    const int c   = rem / NB;
    const int i   = rem % NB;

    const float* hp = H + ((c    ) * BATCH + b) * NB;  // pred
    const float* ht = H + ((c + 3) * BATCH + b) * NB;  // target
    float sp = 0.0f, st = 0.0f;
    #pragma unroll
    for (int k = 0; k < NB; ++k) { sp += hp[k]; st += ht[k]; }

    float val = fabsf(hp[i] / (sp + 1e-7f) - ht[i] / (st + 1e-7f));

    #pragma unroll
    for (int off = 32; off > 0; off >>= 1)
        val += __shfl_down(val, off, 64);

    __shared__ float r[6];
    const int lane = t & 63, wv = t >> 6;
    if (lane == 0) r[wv] = val;
    __syncthreads();
    if (t == 0)
        out[0] = (r[0] + r[1] + r[2] + r[3] + r[4] + r[5]) * (1.0f / 384.0f);
}

extern "C" void kernel_launch(void* const* d_in, const int* in_sizes, int n_in,
                              void* d_out, int out_size, void* d_ws, size_t ws_size,
                              hipStream_t stream)
{
    const float* pred = (const float*)d_in[0];
    const float* tgt  = (const float*)d_in[1];

    unsigned int* partial = (unsigned int*)d_ws;  // 3*8*128*512*4 = 6.29 MB
    float* out2 = (float*)((char*)d_ws + (size_t)3 * BATCH * CHUNKS * FBINS * 4);

    count_kernel<<<dim3(CHUNKS, BATCH), THREADS, 0, stream>>>(pred, tgt, partial);
    combine_kernel<<<dim3(SLICES, 48), THREADS, 0, stream>>>(partial, out2);
    finalize_kernel<<<1, 384, 0, stream>>>(out2, (float*)d_out);
}